// Round 1
// baseline (248.699 us; speedup 1.0000x reference)
//
#include <hip/hip_runtime.h>
#include <hip/hip_bf16.h>

// CausalAttention: B=4, S=2048, d=1024, single head, causal. fp32 I/O, bf16 MFMA inside.
//
// R9: counted-vmcnt software pipeline (T3/T4/T5) for all three GEMMs.
//     R8 diagnosis: QKV at 780 TF with MfmaUtil=31.5%, 0 bank conflicts, near-compulsory
//     FETCH -- schedule-limited, not memory-limited. The 1-phase loop's __syncthreads
//     drains vmcnt(0) every K-tile, exposing ~900cy HBM latency against ~307cy of MFMA.
//     Fix (guide T3/T4): DEPTH-deep LDS ring, raw s_barrier, and counted
//     s_waitcnt vmcnt(6*(DEPTH-1)) so prefetch loads stay in flight across barriers.
//     T5 setprio(1) around the MFMA cluster. Swizzle/fragment/epilogue math unchanged.
//
//     Pipeline ledger (per iter t, slot cur = t%DEPTH):
//       compute(slot cur)                      // reads tile t
//       sched_barrier; s_barrier               // all waves done reading slot cur
//       if (t+DEPTH < nt) STAGE(cur, t+DEPTH)  // refill freed slot (6 or 8 loads/thread)
//       s_waitcnt vmcnt(LPT*min(DEPTH-1, nt-2-t))   // own tile-(t+1) loads landed
//       s_barrier; sched_barrier               // other waves' tile-(t+1) loads landed
//     Never vmcnt(0) in steady state; tail decays 12->6->0 (QKV) / 8->0 (128^2).
//
// Geometry: QKV 256x128/8w DEPTH=3 (144KB LDS, 1 blk/CU -- template precedent m201).
//           scores+PV 128x128/4w DEPTH=2 (64KB -> 2 blk/CU); scores rebalanced to
//           544 equal tiles (was 288 at 256-row tiles -> 2x-ideal makespan at 1 blk/CU).
//
// Pipeline:
//   1) Wq/Wk/Wv fp32 -> bf16 transposed, stacked Wt [3072][1024]
//   2) x fp32 -> bf16 Xb
//   3) {Q,K,V} = Xb * Wt^T       (mode 3, 256x128 tiles, 8 waves, DEPTH=3)
//   4) zero rowsum; Vt = V^T per batch
//   5) E = masked-exp(Q*K^T/32), rowsum accumulated   (mode 1, 128x128, DEPTH=2)
//   6) out(fp32) = (E * V) / rowsum                   (mode 2, 128x128, K clamped)

typedef __bf16 bf16_t;
typedef __bf16 bf16x8 __attribute__((ext_vector_type(8)));
typedef float f32x4 __attribute__((ext_vector_type(4)));

__device__ __forceinline__ void load_lds16(const bf16_t* g, bf16_t* l) {
  __builtin_amdgcn_global_load_lds(
      (__attribute__((address_space(1))) void*)(void*)g,
      (__attribute__((address_space(3))) void*)l,
      16, 0, 0);
}

#define WAITV(N) asm volatile("s_waitcnt vmcnt(" #N ")" ::: "memory")

// C[m][n] = sum_k A[m][k]*B[n][k]  (A:[M][K], B:[N][K] row-major bf16)
// mode: 1 scores: skip tiles above diag, epilogue mask+exp+rowsum
//       2 pv: clamp K at rowBase+BMv, epilogue scale by 1/rowsum | 3 fused qkv split
// LDS swizzle: 16B chunk position p of row r holds global chunk p ^ (r&7);
// fragment reads hit all 32 banks 2-way (free, m136). Conflicts measured 0 (R5-R8).
// Requires nt = Kend/64 >= DEPTH for the static prologue: QKV/scores nt=16,
// PV min nt = 128/64 = 2 with DEPTH=2. OK for all launches here.
template <int BMv, int BNv, int NW, int DEPTH, typename OT>
__global__ __launch_bounds__(NW * 64)
void gemm_nt_pipe(const bf16_t* __restrict__ A, const bf16_t* __restrict__ B,
                  OT* __restrict__ C0, OT* __restrict__ C1, OT* __restrict__ C2,
                  float* __restrict__ RS,
                  int M, int K, int ldc,
                  long strideA, long strideB, long strideC, int mode)
{
  constexpr int MW = BMv / 64;           // wave grid: MW x (NW/MW), 64x64 out per wave
  constexpr int RA = BMv / NW;           // rows staged per wave (A)
  constexpr int RB = BNv / NW;           // rows staged per wave (B)
  constexpr int LPT = RA / 8 + RB / 8;   // global_load_lds per thread per K-tile
  constexpr int SLOT = (BMv + BNv) * 64; // bf16 elems per pipeline slot
  static_assert((DEPTH == 3 && LPT == 6) || (DEPTH == 2 && LPT == 8),
                "vmcnt immediates below assume these configs");

  // XCD-aware remap: pin all x-blocks of an A-panel (y,z) to one XCD.
  // Requires (gridDim.y*gridDim.z) % 8 == 0 -- true for all launches here.
  const int gx = gridDim.x, gy = gridDim.y;
  const int NP = gy * gridDim.z;
  const int P  = NP >> 3;                         // panels per XCD
  const int flat = blockIdx.x + gx * (blockIdx.y + gy * blockIdx.z);
  const int xcd  = flat & 7;
  const int i    = flat >> 3;
  const int pan  = xcd * P + (i % P);
  const int bx   = i / P;
  int by = pan % gy;
  const int bz   = pan / gy;
  if (mode == 1 || mode == 2) by = gy - 1 - by;   // heavy-first

  const int rowBase = by * BMv;
  const int colBase = bx * BNv;
  if (mode == 1 && colBase >= rowBase + BMv) return;  // fully-masked score tile

  __shared__ __align__(16) bf16_t sWS[DEPTH * SLOT];

  A += (size_t)bz * strideA;
  B += (size_t)bz * strideB;
  float* rs_b = RS + (size_t)bz * 2048;

  const int tid  = threadIdx.x;
  const int wave = tid >> 6;
  const int lane = tid & 63;
  const int quad = lane >> 4;
  const int ln16 = lane & 15;

  const int wm = (wave % MW) * 64;
  const int wn = (wave / MW) * 64;

  const int rA = lane >> 3;                       // 0..7 row-in-group
  const int sColOff = ((lane & 7) ^ rA) * 8;      // swizzled chunk offset (elems)
  const bf16_t* pA = A + (size_t)(rowBase + wave * RA + rA) * K + sColOff;
  const bf16_t* pB = B + (size_t)(colBase + wave * RB + rA) * K + sColOff;

  f32x4 acc[4][4] = {};

  const int Kend = (mode == 2) ? (K < rowBase + BMv ? K : rowBase + BMv) : K;
  const int nt = Kend >> 6;

  auto STAGE = [&](int slot, int kt) {
    bf16_t* la = sWS + slot * SLOT + wave * (RA * 64);
    bf16_t* lb = sWS + slot * SLOT + BMv * 64 + wave * (RB * 64);
    const int k0 = kt << 6;
#pragma unroll
    for (int j = 0; j < RA / 8; j++)
      load_lds16(pA + k0 + (size_t)(8 * j) * K, la + j * 512);
#pragma unroll
    for (int j = 0; j < RB / 8; j++)
      load_lds16(pB + k0 + (size_t)(8 * j) * K, lb + j * 512);
  };

  // ---- prologue: fill the ring, wait only for tile 0 (own loads), then barrier.
  if constexpr (DEPTH == 3) {
    STAGE(0, 0); STAGE(1, 1); STAGE(2, 2);
    WAITV(12);
  } else {
    STAGE(0, 0); STAGE(1, 1);
    WAITV(8);
  }
  __builtin_amdgcn_s_barrier();
  __builtin_amdgcn_sched_barrier(0);

  int cur = 0;
  for (int t = 0; t < nt; ++t) {
    const bf16_t* sA = sWS + cur * SLOT;
    const bf16_t* sB = sA + BMv * 64;
#pragma unroll
    for (int kk = 0; kk < 2; kk++) {
      bf16x8 af[4], bfr[4];
#pragma unroll
      for (int mt = 0; mt < 4; mt++) {
        const int row = wm + mt * 16 + ln16;
        af[mt] = *(const bf16x8*)(sA + row * 64 + (((kk * 4 + quad) ^ (row & 7)) * 8));
      }
#pragma unroll
      for (int fn = 0; fn < 4; fn++) {
        const int row = wn + fn * 16 + ln16;
        bfr[fn] = *(const bf16x8*)(sB + row * 64 + (((kk * 4 + quad) ^ (row & 7)) * 8));
      }
      __builtin_amdgcn_s_setprio(1);
#pragma unroll
      for (int mt = 0; mt < 4; mt++)
#pragma unroll
        for (int fn = 0; fn < 4; fn++)
          acc[mt][fn] = __builtin_amdgcn_mfma_f32_16x16x32_bf16(af[mt], bfr[fn], acc[mt][fn], 0, 0, 0);
      __builtin_amdgcn_s_setprio(0);
    }
    __builtin_amdgcn_sched_barrier(0);
    __builtin_amdgcn_s_barrier();              // all waves done reading slot `cur`
    if (t + DEPTH < nt) STAGE(cur, t + DEPTH); // refill freed slot
    const int rem = nt - 2 - t;                // tiles in flight beyond t+1
    if constexpr (DEPTH == 3) {
      if (rem >= 2)      WAITV(12);
      else if (rem == 1) WAITV(6);
      else if (rem == 0) WAITV(0);
    } else {
      if (rem >= 1)      WAITV(8);
      else if (rem == 0) WAITV(0);
    }
    __builtin_amdgcn_s_barrier();              // other waves' tile-(t+1) loads landed
    __builtin_amdgcn_sched_barrier(0);
    cur = (cur == DEPTH - 1) ? 0 : cur + 1;
  }

  // output target: mode 3 splits by 1024-col groups (uniform per block)
  OT* Cw = C0;
  int cb = colBase;
  if (mode == 3) {
    const int which = colBase >> 10;
    Cw = (which == 0) ? C0 : (which == 1) ? C1 : C2;
    cb = colBase & 1023;
  }
  Cw += (size_t)bz * strideC;

  // epilogue: C/D layout col = lane&15, row = quad*4 + r  [measured m89/m91]
#pragma unroll
  for (int mt = 0; mt < 4; mt++) {
#pragma unroll
    for (int r = 0; r < 4; r++) {
      const int row = rowBase + wm + mt * 16 + quad * 4 + r;
      float rsum = 0.0f;
      float rinv = 1.0f;
      if (mode == 2) rinv = 1.0f / rs_b[row];
#pragma unroll
      for (int fn = 0; fn < 4; fn++) {
        const int col = cb + wn + fn * 16 + ln16;
        float v = acc[mt][fn][r];
        if (mode == 1) {
          const float e = (col <= row) ? __expf(v * 0.03125f) : 0.0f;  // s/sqrt(1024)
          rsum += e;
          v = e;
        } else if (mode == 2) {
          v *= rinv;
        }
        Cw[(size_t)row * ldc + col] = (OT)v;
      }
      if (mode == 1) {
        rsum += __shfl_xor(rsum, 1, 64);
        rsum += __shfl_xor(rsum, 2, 64);
        rsum += __shfl_xor(rsum, 4, 64);
        rsum += __shfl_xor(rsum, 8, 64);
        if (ln16 == 0) atomicAdd(rs_b + row, rsum);
      }
    }
  }
}

// three fp32 [D][D] -> bf16 transposed, stacked [3D][D]; z selects source
__global__ __launch_bounds__(256)
void transpose_cvt3(const float* __restrict__ w0, const float* __restrict__ w1,
                    const float* __restrict__ w2, bf16_t* __restrict__ out, int D)
{
  const float* in = (blockIdx.z == 0) ? w0 : (blockIdx.z == 1) ? w1 : w2;
  bf16_t* o = out + (size_t)blockIdx.z * D * D;
  __shared__ float tile[32][33];
  const int c0 = blockIdx.x * 32, r0 = blockIdx.y * 32;
  const int tx = threadIdx.x, ty = threadIdx.y;  // (32, 8)
#pragma unroll
  for (int i = 0; i < 32; i += 8)
    tile[ty + i][tx] = in[(size_t)(r0 + ty + i) * D + (c0 + tx)];
  __syncthreads();
#pragma unroll
  for (int i = 0; i < 32; i += 8)
    o[(size_t)(c0 + ty + i) * D + (r0 + tx)] = (bf16_t)tile[tx][ty + i];
}

// bf16 [R][C] -> bf16 transposed [C][R]; batched via blockIdx.z
__global__ __launch_bounds__(256)
void transpose16(const unsigned short* __restrict__ in, unsigned short* __restrict__ out,
                 int R, int C)
{
  __shared__ unsigned short tile[32][33];
  const size_t bo = (size_t)blockIdx.z * R * C;
  const int c0 = blockIdx.x * 32, r0 = blockIdx.y * 32;
  const int tx = threadIdx.x, ty = threadIdx.y;  // (32, 8)
#pragma unroll
  for (int i = 0; i < 32; i += 8)
    tile[ty + i][tx] = in[bo + (size_t)(r0 + ty + i) * C + (c0 + tx)];
  __syncthreads();
#pragma unroll
  for (int i = 0; i < 32; i += 8)
    out[bo + (size_t)(c0 + ty + i) * R + (r0 + tx)] = tile[tx][ty + i];
}

// fp32 -> bf16 elementwise, 8/thread, vector load+store
__global__ __launch_bounds__(256)
void cvt_f32_bf16(const float* __restrict__ in, bf16_t* __restrict__ out, long n)
{
  long i = ((long)blockIdx.x * 256 + threadIdx.x) * 8;
  if (i + 7 < n) {
    float4 a = *(const float4*)(in + i);
    float4 b = *(const float4*)(in + i + 4);
    bf16x8 o;
    o[0] = (bf16_t)a.x; o[1] = (bf16_t)a.y; o[2] = (bf16_t)a.z; o[3] = (bf16_t)a.w;
    o[4] = (bf16_t)b.x; o[5] = (bf16_t)b.y; o[6] = (bf16_t)b.z; o[7] = (bf16_t)b.w;
    *(bf16x8*)(out + i) = o;
  }
}

__global__ __launch_bounds__(256)
void zero_f32(float* __restrict__ p, int n)
{
  const int i = blockIdx.x * 256 + threadIdx.x;
  if (i < n) p[i] = 0.0f;
}

extern "C" void kernel_launch(void* const* d_in, const int* in_sizes, int n_in,
                              void* d_out, int out_size, void* d_ws, size_t ws_size,
                              hipStream_t stream) {
  const float* x  = (const float*)d_in[0];
  const float* Wq = (const float*)d_in[1];
  const float* Wk = (const float*)d_in[2];
  const float* Wv = (const float*)d_in[3];
  float* out = (float*)d_out;

  const int Bb = 4, S = 2048, D = 1024;
  const int M = Bb * S;  // 8192

  // ws (bf16 elems): Q | K | Vt | Wt(3*D*D) | Xb | V   = 90,177,536 B (proven fit)
  // Sc (Bb*S*S == 2*M*D) aliases [Xb|V]; rowsum (32 KB f32) reuses Wt (dead post-QKV).
  bf16_t* ws = (bf16_t*)d_ws;
  bf16_t* Q   = ws;
  bf16_t* Kp  = Q  + (size_t)M * D;
  bf16_t* Vt  = Kp + (size_t)M * D;
  bf16_t* Wt  = Vt + (size_t)M * D;          // [3072][1024] stacked
  bf16_t* Xb  = Wt + 3 * (size_t)D * D;
  bf16_t* V   = Xb + (size_t)M * D;
  bf16_t* Sc  = Xb;
  float*  rowsum = (float*)Wt;               // Bb*S floats

  const dim3 tb(32, 8);

  // 1) W fp32 -> bf16 transposed, stacked
  transpose_cvt3<<<dim3(D / 32, D / 32, 3), tb, 0, stream>>>(Wq, Wk, Wv, Wt, D);

  // 2) x -> bf16
  cvt_f32_bf16<<<dim3((M * D) / (256 * 8)), dim3(256), 0, stream>>>(x, Xb, (long)M * D);

  // 3) fused projections: {Q,K,V} = Xb * Wt^T  (grid 24 x 32; 32 panels -> 4/XCD)
  gemm_nt_pipe<256, 128, 8, 3, bf16_t><<<dim3(3 * D / 128, M / 256, 1), dim3(512), 0, stream>>>(
      Xb, Wt, Q, Kp, V, rowsum, M, D, D, 0, 0, 0, 3);

  // 4) zero rowsum (Wt dead now); Vt per batch
  zero_f32<<<dim3(M / 256), dim3(256), 0, stream>>>(rowsum, M);
  transpose16<<<dim3(D / 32, S / 32, Bb), tb, 0, stream>>>((const unsigned short*)V, (unsigned short*)Vt, S, D);

  // 5) E = masked-exp(Q*K^T/32) + rowsum  (grid 16 x 16 x 4; 64 panels -> 8/XCD)
  gemm_nt_pipe<128, 128, 4, 2, bf16_t><<<dim3(S / 128, S / 128, Bb), dim3(256), 0, stream>>>(
      Q, Kp, Sc, Sc, Sc, rowsum, S, D, S, (long)S * D, (long)S * D, (long)S * S, 1);

  // 6) out(fp32) = (E*V)/rowsum  (grid 8 x 16 x 4; 64 panels -> 8/XCD)
  gemm_nt_pipe<128, 128, 4, 2, float><<<dim3(D / 128, S / 128, Bb), dim3(256), 0, stream>>>(
      Sc, Vt, out, out, out, rowsum, S, S, D, (long)S * S, (long)D * S, (long)S * D, 2);
}

// Round 2
// 238.964 us; speedup vs baseline: 1.0407x; 1.0407x over previous
//
#include <hip/hip_runtime.h>
#include <hip/hip_bf16.h>

// CausalAttention: B=4, S=2048, d=1024, single head, causal. fp32 I/O, bf16 MFMA inside.
//
// R10: proper 256^2 8-phase schedule (m201 template) for the two K=1024 GEMMs
//      (QKV mode 3, scores mode 1). PV (mode 2) reverts to the R8-proven 2-phase
//      128^2 kernel (variable-K; 256^2 tiles would worsen its makespan).
//
//      R9 post-mortem: coarse whole-tile pipeline = m196's known-bad case (-10%),
//      and 144KB LDS killed the 3-block/CU TLP that was actually hiding latency in R8.
//
//      8-phase design (fully ledger-verified):
//      - BM=BN=256, BK=64, 8 waves, per-wave 128x64 out, acc[8][4] f32x4.
//      - Wave rows remapped so phase q reads ONLY half-tiles A(q>>1), B(q&1):
//        A-frag rows = (mt>>2)*128 + wm + (mt&3)*16, wm=(wave&1)*64
//        B-frag rows = (fn>>1)*128 + wn + (fn&1)*16, wn=(wave>>1)*32
//        -> A0 free after q1, B0 after q2, A1/B1 after q3 (reg-held, lgkm-drained
//        before each phase's MFMA, hence before the next barrier).
//      - Stage 1 half-tile/phase (2 global_load_lds/thread) into the freed region:
//        q0: A1(t+1), q1: B1(t+1), q2: A0(t+2), q3: B0(t+2). Slots: tile t in slot t&1.
//      - Waits: q0 vmcnt(8) [A0(t),B0(t) landed; newest 4 half-tiles may fly],
//        q1 vmcnt(6) [B1(t),A1(t) landed]; q2,q3 need none (covered by q1).
//        Needed loads are issued 4-6 phases (~1200cy) ahead of use vs ~900cy HBM.
//        NEVER vmcnt(0) in the loop (T4). Tail: stage targets clamp to nt-1
//        (harmless rewrite of freed regions; ledger stays uniform); vmcnt(0) after loop.
//      - setprio(1) around each 16-MFMA cluster (T5); barriers are asm s_barrier with
//        "memory" clobber so ds_reads/stages can't be compiler-hoisted across phases.
//
// Pipeline:
//   1) Wq/Wk/Wv fp32 -> bf16 transposed, stacked Wt [3072][1024]
//   2) x fp32 -> bf16 Xb
//   3) {Q,K,V} = Xb * Wt^T       (8-phase, 256^2, mode 3, grid 12x32)
//   4) zero rowsum; Vt = V^T per batch
//   5) E = masked-exp(Q*K^T/32), rowsum accumulated  (8-phase, 256^2, mode 1, grid 8x8x4)
//   6) out(fp32) = (E * V) / rowsum                  (2-phase 128^2, mode 2, K clamped)

typedef __bf16 bf16_t;
typedef __bf16 bf16x8 __attribute__((ext_vector_type(8)));
typedef float f32x4 __attribute__((ext_vector_type(4)));

__device__ __forceinline__ void load_lds16(const bf16_t* g, bf16_t* l) {
  __builtin_amdgcn_global_load_lds(
      (__attribute__((address_space(1))) void*)(void*)g,
      (__attribute__((address_space(3))) void*)l,
      16, 0, 0);
}

#define WAITV(N) asm volatile("s_waitcnt vmcnt(" #N ")" ::: "memory")
#define BARM()   asm volatile("s_barrier" ::: "memory")

// ---------------- 8-phase 256^2 kernel (modes 3 = qkv split, 1 = scores) ----------
// LDS swizzle: 16B chunk position p of row r holds global chunk p ^ (r&7);
// reads are 2-way (free). Same scheme as R5-R8, conflicts measured 0.
template <typename OT>
__global__ __launch_bounds__(512, 2)
void gemm_nt_8ph(const bf16_t* __restrict__ A, const bf16_t* __restrict__ B,
                 OT* __restrict__ C0, OT* __restrict__ C1, OT* __restrict__ C2,
                 float* __restrict__ RS, int K, int ldc,
                 long strideA, long strideB, long strideC, int mode)
{
  constexpr int SLOT = 2 * 256 * 64;   // bf16 elems per slot (A 16K + B 16K) = 32768

  // XCD-aware remap: pin all x-blocks of an A-panel (y,z) to one XCD.
  // Requires (gridDim.y*gridDim.z) % 8 == 0 -- true for both launches (32).
  const int gx = gridDim.x, gy = gridDim.y;
  const int NP = gy * gridDim.z;
  const int P  = NP >> 3;
  const int flat = blockIdx.x + gx * (blockIdx.y + gy * blockIdx.z);
  const int xcd  = flat & 7;
  const int ii   = flat >> 3;
  const int pan  = xcd * P + (ii % P);
  const int bx   = ii / P;
  int by = pan % gy;
  const int bz   = pan / gy;
  if (mode == 1) by = gy - 1 - by;                 // heavy-first
  const int rowBase = by * 256;
  const int colBase = bx * 256;
  if (mode == 1 && colBase >= rowBase + 256) return;

  __shared__ __align__(16) bf16_t sWS[2 * SLOT];   // 128 KiB

  A += (size_t)bz * strideA;
  B += (size_t)bz * strideB;
  float* rs_b = RS + (size_t)bz * 2048;

  const int tid  = threadIdx.x;
  const int wave = tid >> 6;
  const int lane = tid & 63;
  const int quad = lane >> 4;
  const int ln16 = lane & 15;
  const int wm = (wave & 1) * 64;                  // M offset within each 128-half
  const int wn = (wave >> 1) * 32;                 // N offset within each 128-half

  // staging: thread t covers row (t>>3) of a 64-row group, swizzled chunk (t&7)^(row&7)
  const int srow = tid >> 3;
  const int schk = (tid & 7) ^ (srow & 7);
  const bf16_t* pA = A + (size_t)(rowBase + srow) * K + schk * 8;
  const bf16_t* pB = B + (size_t)(colBase + srow) * K + schk * 8;
  bf16_t* const ldsW = sWS + wave * 512;           // per-wave linear dest base

  f32x4 acc[8][4] = {};
  const int nt = K >> 6;                           // 16 for both launches

  auto STG = [&](int side, int hh, int kt, int s) {
    const bf16_t* p = (side ? pB : pA) + (size_t)(hh * 128) * K + (size_t)kt * 64;
    bf16_t* l = ldsW + s * SLOT + side * 16384 + hh * 8192;
    load_lds16(p, l);
    load_lds16(p + (size_t)64 * K, l + 4096);
  };

  // prologue: A0(0) B0(0) A1(0) B1(0) A0(1) B0(1)  -- 12 load instrs/thread
  STG(0, 0, 0, 0); STG(1, 0, 0, 0); STG(0, 1, 0, 0); STG(1, 1, 0, 0);
  STG(0, 0, 1, 1); STG(1, 0, 1, 1);

  bf16x8 af[2][4], bfr[2][4];

  for (int t = 0; t < nt; ++t) {
    const int s  = t & 1;
    const bf16_t* sAp = sWS + s * SLOT;
    const bf16_t* sBp = sAp + 16384;
    const int kt1 = (t + 1 < nt) ? t + 1 : nt - 1;   // clamp: tail rewrites freed regions
    const int s1  = (t + 1) & 1;
    const int kt2 = (t + 2 < nt) ? t + 2 : nt - 1;

    // ---- q0: read A0,B0; stage A1(t+1); MFMA quadrant [mt0-3][fn0-1]
    WAITV(8); BARM();
#pragma unroll
    for (int kk = 0; kk < 2; kk++)
#pragma unroll
      for (int m = 0; m < 4; m++) {
        const int row = wm + m * 16 + ln16;
        af[kk][m] = *(const bf16x8*)(sAp + row * 64 + (((kk * 4 + quad) ^ (row & 7)) * 8));
      }
#pragma unroll
    for (int kk = 0; kk < 2; kk++)
#pragma unroll
      for (int f = 0; f < 2; f++) {
        const int row = wn + f * 16 + ln16;
        bfr[kk][f] = *(const bf16x8*)(sBp + row * 64 + (((kk * 4 + quad) ^ (row & 7)) * 8));
      }
    STG(0, 1, kt1, s1);
    __builtin_amdgcn_s_setprio(1);
#pragma unroll
    for (int kk = 0; kk < 2; kk++)
#pragma unroll
      for (int m = 0; m < 4; m++)
#pragma unroll
        for (int f = 0; f < 2; f++)
          acc[m][f] = __builtin_amdgcn_mfma_f32_16x16x32_bf16(af[kk][m], bfr[kk][f], acc[m][f], 0, 0, 0);
    __builtin_amdgcn_s_setprio(0);

    // ---- q1: read B1; stage B1(t+1); MFMA [mt0-3][fn2-3]
    WAITV(6); BARM();
#pragma unroll
    for (int kk = 0; kk < 2; kk++)
#pragma unroll
      for (int f = 0; f < 2; f++) {
        const int row = 128 + wn + f * 16 + ln16;
        bfr[kk][2 + f] = *(const bf16x8*)(sBp + row * 64 + (((kk * 4 + quad) ^ (row & 7)) * 8));
      }
    STG(1, 1, kt1, s1);
    __builtin_amdgcn_s_setprio(1);
#pragma unroll
    for (int kk = 0; kk < 2; kk++)
#pragma unroll
      for (int m = 0; m < 4; m++)
#pragma unroll
        for (int f = 0; f < 2; f++)
          acc[m][2 + f] = __builtin_amdgcn_mfma_f32_16x16x32_bf16(af[kk][m], bfr[kk][2 + f], acc[m][2 + f], 0, 0, 0);
    __builtin_amdgcn_s_setprio(0);

    // ---- q2: read A1 (overwrite af); stage A0(t+2); MFMA [mt4-7][fn0-1]
    BARM();
#pragma unroll
    for (int kk = 0; kk < 2; kk++)
#pragma unroll
      for (int m = 0; m < 4; m++) {
        const int row = 128 + wm + m * 16 + ln16;
        af[kk][m] = *(const bf16x8*)(sAp + row * 64 + (((kk * 4 + quad) ^ (row & 7)) * 8));
      }
    STG(0, 0, kt2, s);
    __builtin_amdgcn_s_setprio(1);
#pragma unroll
    for (int kk = 0; kk < 2; kk++)
#pragma unroll
      for (int m = 0; m < 4; m++)
#pragma unroll
        for (int f = 0; f < 2; f++)
          acc[4 + m][f] = __builtin_amdgcn_mfma_f32_16x16x32_bf16(af[kk][m], bfr[kk][f], acc[4 + m][f], 0, 0, 0);
    __builtin_amdgcn_s_setprio(0);

    // ---- q3: no ds_reads; stage B0(t+2); MFMA [mt4-7][fn2-3]
    BARM();
    STG(1, 0, kt2, s);
    __builtin_amdgcn_s_setprio(1);
#pragma unroll
    for (int kk = 0; kk < 2; kk++)
#pragma unroll
      for (int m = 0; m < 4; m++)
#pragma unroll
        for (int f = 0; f < 2; f++)
          acc[4 + m][2 + f] = __builtin_amdgcn_mfma_f32_16x16x32_bf16(af[kk][m], bfr[kk][2 + f], acc[4 + m][2 + f], 0, 0, 0);
    __builtin_amdgcn_s_setprio(0);
  }
  WAITV(0);   // drain clamped tail stages before exit

  // epilogue
  OT* Cw = C0;
  int cb = colBase;
  if (mode == 3) {
    const int which = colBase >> 10;                 // 256-col tiles never span matrices
    Cw = (which == 0) ? C0 : (which == 1) ? C1 : C2;
    cb = colBase & 1023;
  }
  Cw += (size_t)bz * strideC;

  // C/D layout: col = lane&15, row = quad*4 + r  [m89/m91]
#pragma unroll
  for (int m2 = 0; m2 < 8; m2++) {
#pragma unroll
    for (int r = 0; r < 4; r++) {
      const int row = rowBase + (m2 >> 2) * 128 + wm + (m2 & 3) * 16 + quad * 4 + r;
      float rsum = 0.0f;
#pragma unroll
      for (int f2 = 0; f2 < 4; f2++) {
        const int col = cb + (f2 >> 1) * 128 + wn + (f2 & 1) * 16 + ln16;
        float v = acc[m2][f2][r];
        if (mode == 1) {
          const float e = (col <= row) ? __expf(v * 0.03125f) : 0.0f;  // s/sqrt(1024)
          rsum += e;
          v = e;
        }
        Cw[(size_t)row * ldc + col] = (OT)v;
      }
      if (mode == 1) {
        rsum += __shfl_xor(rsum, 1, 64);
        rsum += __shfl_xor(rsum, 2, 64);
        rsum += __shfl_xor(rsum, 4, 64);
        rsum += __shfl_xor(rsum, 8, 64);
        if (ln16 == 0) atomicAdd(rs_b + row, rsum);
      }
    }
  }
}

// ---------------- R8 2-phase drain kernel (mode 2 = PV only) ----------------------
template <int BMv, int BNv, int NW, typename OT>
__global__ __launch_bounds__(NW * 64)
void gemm_nt_bf16(const bf16_t* __restrict__ A, const bf16_t* __restrict__ B,
                  OT* __restrict__ C0, OT* __restrict__ C1, OT* __restrict__ C2,
                  float* __restrict__ RS,
                  int M, int K, int ldc,
                  long strideA, long strideB, long strideC, int mode)
{
  constexpr int MW = BMv / 64;
  constexpr int RA = BMv / NW;
  constexpr int RB = BNv / NW;

  const int gx = gridDim.x, gy = gridDim.y;
  const int NP = gy * gridDim.z;
  const int P  = NP >> 3;
  const int flat = blockIdx.x + gx * (blockIdx.y + gy * blockIdx.z);
  const int xcd  = flat & 7;
  const int i    = flat >> 3;
  const int pan  = xcd * P + (i % P);
  const int bx   = i / P;
  int by = pan % gy;
  const int bz   = pan / gy;
  if (mode == 1 || mode == 2) by = gy - 1 - by;

  const int rowBase = by * BMv;
  const int colBase = bx * BNv;
  if (mode == 1 && colBase >= rowBase + BMv) return;

  __shared__ __align__(16) bf16_t sA[BMv * 64];
  __shared__ __align__(16) bf16_t sB[BNv * 64];

  A += (size_t)bz * strideA;
  B += (size_t)bz * strideB;
  float* rs_b = RS + (size_t)bz * 2048;

  const int tid  = threadIdx.x;
  const int wave = tid >> 6;
  const int lane = tid & 63;
  const int quad = lane >> 4;
  const int ln16 = lane & 15;

  const int wm = (wave % MW) * 64;
  const int wn = (wave / MW) * 64;

  const int rA = lane >> 3;
  const int sColOff = ((lane & 7) ^ rA) * 8;
  const bf16_t* pA = A + (size_t)(rowBase + wave * RA + rA) * K + sColOff;
  const bf16_t* pB = B + (size_t)(colBase + wave * RB + rA) * K + sColOff;
  bf16_t* ldsA = sA + wave * RA * 64;
  bf16_t* ldsB = sB + wave * RB * 64;

  f32x4 acc[4][4] = {};

  const int Kend = (mode == 2) ? (K < rowBase + BMv ? K : rowBase + BMv) : K;

  for (int k0 = 0; k0 < Kend; k0 += 64) {
#pragma unroll
    for (int j = 0; j < RA / 8; j++)
      load_lds16(pA + k0 + (size_t)(8 * j) * K, ldsA + j * 512);
#pragma unroll
    for (int j = 0; j < RB / 8; j++)
      load_lds16(pB + k0 + (size_t)(8 * j) * K, ldsB + j * 512);
    __syncthreads();

#pragma unroll
    for (int kk = 0; kk < 2; kk++) {
      bf16x8 af[4], bfr[4];
#pragma unroll
      for (int mt = 0; mt < 4; mt++) {
        const int row = wm + mt * 16 + ln16;
        af[mt] = *(const bf16x8*)(sA + row * 64 + (((kk * 4 + quad) ^ (row & 7)) * 8));
      }
#pragma unroll
      for (int nt = 0; nt < 4; nt++) {
        const int row = wn + nt * 16 + ln16;
        bfr[nt] = *(const bf16x8*)(sB + row * 64 + (((kk * 4 + quad) ^ (row & 7)) * 8));
      }
#pragma unroll
      for (int mt = 0; mt < 4; mt++)
#pragma unroll
        for (int nt = 0; nt < 4; nt++)
          acc[mt][nt] = __builtin_amdgcn_mfma_f32_16x16x32_bf16(af[mt], bfr[nt], acc[mt][nt], 0, 0, 0);
    }
    __syncthreads();
  }

  OT* Cw = C0;
  int cb = colBase;
  if (mode == 3) {
    const int which = colBase >> 10;
    Cw = (which == 0) ? C0 : (which == 1) ? C1 : C2;
    cb = colBase & 1023;
  }
  Cw += (size_t)bz * strideC;

#pragma unroll
  for (int mt = 0; mt < 4; mt++) {
#pragma unroll
    for (int r = 0; r < 4; r++) {
      const int row = rowBase + wm + mt * 16 + quad * 4 + r;
      float rsum = 0.0f;
      float rinv = 1.0f;
      if (mode == 2) rinv = 1.0f / rs_b[row];
#pragma unroll
      for (int nt = 0; nt < 4; nt++) {
        const int col = cb + wn + nt * 16 + ln16;
        float v = acc[mt][nt][r];
        if (mode == 1) {
          const float e = (col <= row) ? __expf(v * 0.03125f) : 0.0f;
          rsum += e;
          v = e;
        } else if (mode == 2) {
          v *= rinv;
        }
        Cw[(size_t)row * ldc + col] = (OT)v;
      }
      if (mode == 1) {
        rsum += __shfl_xor(rsum, 1, 64);
        rsum += __shfl_xor(rsum, 2, 64);
        rsum += __shfl_xor(rsum, 4, 64);
        rsum += __shfl_xor(rsum, 8, 64);
        if (ln16 == 0) atomicAdd(rs_b + row, rsum);
      }
    }
  }
}

// three fp32 [D][D] -> bf16 transposed, stacked [3D][D]; z selects source
__global__ __launch_bounds__(256)
void transpose_cvt3(const float* __restrict__ w0, const float* __restrict__ w1,
                    const float* __restrict__ w2, bf16_t* __restrict__ out, int D)
{
  const float* in = (blockIdx.z == 0) ? w0 : (blockIdx.z == 1) ? w1 : w2;
  bf16_t* o = out + (size_t)blockIdx.z * D * D;
  __shared__ float tile[32][33];
  const int c0 = blockIdx.x * 32, r0 = blockIdx.y * 32;
  const int tx = threadIdx.x, ty = threadIdx.y;  // (32, 8)
#pragma unroll
  for (int i = 0; i < 32; i += 8)
    tile[ty + i][tx] = in[(size_t)(r0 + ty + i) * D + (c0 + tx)];
  __syncthreads();
#pragma unroll
  for (int i = 0; i < 32; i += 8)
    o[(size_t)(c0 + ty + i) * D + (r0 + tx)] = (bf16_t)tile[tx][ty + i];
}

// bf16 [R][C] -> bf16 transposed [C][R]; batched via blockIdx.z
__global__ __launch_bounds__(256)
void transpose16(const unsigned short* __restrict__ in, unsigned short* __restrict__ out,
                 int R, int C)
{
  __shared__ unsigned short tile[32][33];
  const size_t bo = (size_t)blockIdx.z * R * C;
  const int c0 = blockIdx.x * 32, r0 = blockIdx.y * 32;
  const int tx = threadIdx.x, ty = threadIdx.y;  // (32, 8)
#pragma unroll
  for (int i = 0; i < 32; i += 8)
    tile[ty + i][tx] = in[bo + (size_t)(r0 + ty + i) * C + (c0 + tx)];
  __syncthreads();
#pragma unroll
  for (int i = 0; i < 32; i += 8)
    out[bo + (size_t)(c0 + ty + i) * R + (r0 + tx)] = tile[tx][ty + i];
}

// fp32 -> bf16 elementwise, 8/thread, vector load+store
__global__ __launch_bounds__(256)
void cvt_f32_bf16(const float* __restrict__ in, bf16_t* __restrict__ out, long n)
{
  long i = ((long)blockIdx.x * 256 + threadIdx.x) * 8;
  if (i + 7 < n) {
    float4 a = *(const float4*)(in + i);
    float4 b = *(const float4*)(in + i + 4);
    bf16x8 o;
    o[0] = (bf16_t)a.x; o[1] = (bf16_t)a.y; o[2] = (bf16_t)a.z; o[3] = (bf16_t)a.w;
    o[4] = (bf16_t)b.x; o[5] = (bf16_t)b.y; o[6] = (bf16_t)b.z; o[7] = (bf16_t)b.w;
    *(bf16x8*)(out + i) = o;
  }
}

__global__ __launch_bounds__(256)
void zero_f32(float* __restrict__ p, int n)
{
  const int i = blockIdx.x * 256 + threadIdx.x;
  if (i < n) p[i] = 0.0f;
}

extern "C" void kernel_launch(void* const* d_in, const int* in_sizes, int n_in,
                              void* d_out, int out_size, void* d_ws, size_t ws_size,
                              hipStream_t stream) {
  const float* x  = (const float*)d_in[0];
  const float* Wq = (const float*)d_in[1];
  const float* Wk = (const float*)d_in[2];
  const float* Wv = (const float*)d_in[3];
  float* out = (float*)d_out;

  const int Bb = 4, S = 2048, D = 1024;
  const int M = Bb * S;  // 8192

  // ws (bf16 elems): Q | K | Vt | Wt(3*D*D) | Xb | V   = 90,177,536 B (proven fit)
  // Sc (Bb*S*S == 2*M*D) aliases [Xb|V]; rowsum (32 KB f32) reuses Wt (dead post-QKV).
  bf16_t* ws = (bf16_t*)d_ws;
  bf16_t* Q   = ws;
  bf16_t* Kp  = Q  + (size_t)M * D;
  bf16_t* Vt  = Kp + (size_t)M * D;
  bf16_t* Wt  = Vt + (size_t)M * D;          // [3072][1024] stacked
  bf16_t* Xb  = Wt + 3 * (size_t)D * D;
  bf16_t* V   = Xb + (size_t)M * D;
  bf16_t* Sc  = Xb;
  float*  rowsum = (float*)Wt;               // Bb*S floats

  const dim3 tb(32, 8);

  // 1) W fp32 -> bf16 transposed, stacked
  transpose_cvt3<<<dim3(D / 32, D / 32, 3), tb, 0, stream>>>(Wq, Wk, Wv, Wt, D);

  // 2) x -> bf16
  cvt_f32_bf16<<<dim3((M * D) / (256 * 8)), dim3(256), 0, stream>>>(x, Xb, (long)M * D);

  // 3) fused projections: {Q,K,V} = Xb * Wt^T  (8-phase; grid 12x32, 384 tiles)
  gemm_nt_8ph<bf16_t><<<dim3(3 * D / 256, M / 256, 1), dim3(512), 0, stream>>>(
      Xb, Wt, Q, Kp, V, rowsum, D, D, 0, 0, 0, 3);

  // 4) zero rowsum (Wt dead now); Vt per batch
  zero_f32<<<dim3(M / 256), dim3(256), 0, stream>>>(rowsum, M);
  transpose16<<<dim3(D / 32, S / 32, Bb), tb, 0, stream>>>((const unsigned short*)V, (unsigned short*)Vt, S, D);

  // 5) E = masked-exp(Q*K^T/32) + rowsum  (8-phase; grid 8x8x4, 144 active tiles)
  gemm_nt_8ph<bf16_t><<<dim3(S / 256, S / 256, Bb), dim3(512), 0, stream>>>(
      Q, Kp, Sc, Sc, Sc, rowsum, D, S, (long)S * D, (long)S * D, (long)S * S, 1);

  // 6) out(fp32) = (E*V)/rowsum  (2-phase; grid 8 x 16 x 4; 64 panels -> 8/XCD)
  gemm_nt_bf16<128, 128, 4, float><<<dim3(D / 128, S / 128, Bb), dim3(256), 0, stream>>>(
      Sc, Vt, out, out, out, rowsum, S, S, D, (long)S * S, (long)D * S, (long)S * D, 2);
}